// Round 3
// baseline (447.609 us; speedup 1.0000x reference)
//
#include <hip/hip_runtime.h>

#define NS 115              // contributing samples (S=116, last one unused)
#define WEPS 5e-5f          // per-sample color skip
#define LOG_TSKIP -6.9078f  // chunk1 skip when T < 1e-3
#define NCELLS (128*128*128)
#define PACK_BYTES ((size_t)NCELLS * 64)

typedef float f32x4 __attribute__((ext_vector_type(4)));
typedef float f32x2 __attribute__((ext_vector_type(2)));
typedef _Float16 h16x8 __attribute__((ext_vector_type(8)));
typedef _Float16 h16x4 __attribute__((ext_vector_type(4)));

struct SH9 { float a,b,c,d,e,f,g,h,i; };

__device__ __forceinline__ f32x4 load4(const float* p) { f32x4 v; __builtin_memcpy(&v, p, 16); return v; }
__device__ __forceinline__ f32x2 load2(const float* p) { f32x2 v; __builtin_memcpy(&v, p, 8);  return v; }
__device__ __forceinline__ h16x8 load8h(const _Float16* p) { h16x8 v; __builtin_memcpy(&v, p, 16); return v; }
__device__ __forceinline__ h16x4 load4h(const _Float16* p) { h16x4 v; __builtin_memcpy(&v, p, 8);  return v; }

__device__ __forceinline__ void pos_to_cell(float px, float py, float pz,
                                            int& ibase, float* wxs, float* wys, float* wzs) {
    px = fminf(fmaxf(px, 0.0f), 126.9999f);
    py = fminf(fmaxf(py, 0.0f), 126.9999f);
    pz = fminf(fmaxf(pz, 0.0f), 126.9999f);
    int ix = (int)px, iy = (int)py, iz = (int)pz;
    float wx = px - (float)ix, wy = py - (float)iy, wz = pz - (float)iz;
    ibase = (ix << 14) + (iy << 7) + iz;
    wxs[0] = 1.0f - wx; wxs[1] = wx;
    wys[0] = 1.0f - wy; wys[1] = wy;
    wzs[0] = 1.0f - wz; wzs[1] = wz;
}

// opacity trilerp on the ORIGINAL f32 array (keeps exponent-path precision);
// z-adjacent corners via dwordx2.
__device__ __forceinline__ float eval_op(float px, float py, float pz,
                                         const float* __restrict__ opa) {
    int ibase; float wxs[2], wys[2], wzs[2];
    pos_to_cell(px, py, pz, ibase, wxs, wys, wzs);
    float op = 0.0f;
    #pragma unroll
    for (int cx = 0; cx < 2; ++cx)
    #pragma unroll
    for (int cy = 0; cy < 2; ++cy) {
        int idx = ibase + (cx << 14) + (cy << 7);
        f32x2 pr = load2(opa + idx);
        float wxy = wxs[cx] * wys[cy];
        op = fmaf(wxy * wzs[0], pr.x, op);
        op = fmaf(wxy * wzs[1], pr.y, op);
    }
    return fminf(fmaxf(op, 0.0f), 100000.0f);
}

// ---- packed fp16 color: one 64-B aligned cache line per corner ----
__device__ __forceinline__ void eval_color_h(float px, float py, float pz,
                                             const _Float16* __restrict__ pack,
                                             const SH9& sh,
                                             float& cr, float& cg, float& cb) {
    int ibase; float wxs[2], wys[2], wzs[2];
    pos_to_cell(px, py, pz, ibase, wxs, wys, wzs);
    float r = 0.0f, g = 0.0f, b = 0.0f;
    #pragma unroll
    for (int cx = 0; cx < 2; ++cx)
    #pragma unroll
    for (int cy = 0; cy < 2; ++cy)
    #pragma unroll
    for (int cz = 0; cz < 2; ++cz) {
        int idx = ibase + (cx << 14) + (cy << 7) + cz;
        float wc = wxs[cx] * wys[cy] * wzs[cz];
        const _Float16* cp = pack + ((size_t)idx << 5);
        h16x8 v0 = load8h(cp);        // ch 0..7
        h16x8 v1 = load8h(cp + 8);    // ch 8..15
        h16x8 v2 = load8h(cp + 16);   // ch 16..23
        h16x4 v3 = load4h(cp + 24);   // ch 24..26 (+pad)
        float c0 = sh.a*(float)v0[0] + sh.b*(float)v0[1] + sh.c*(float)v0[2] + sh.d*(float)v0[3]
                 + sh.e*(float)v0[4] + sh.f*(float)v0[5] + sh.g*(float)v0[6] + sh.h*(float)v0[7]
                 + sh.i*(float)v1[0];
        float c1 = sh.a*(float)v1[1] + sh.b*(float)v1[2] + sh.c*(float)v1[3] + sh.d*(float)v1[4]
                 + sh.e*(float)v1[5] + sh.f*(float)v1[6] + sh.g*(float)v1[7] + sh.h*(float)v2[0]
                 + sh.i*(float)v2[1];
        float c2 = sh.a*(float)v2[2] + sh.b*(float)v2[3] + sh.c*(float)v2[4] + sh.d*(float)v2[5]
                 + sh.e*(float)v2[6] + sh.f*(float)v2[7] + sh.g*(float)v3[0] + sh.h*(float)v3[1]
                 + sh.i*(float)v3[2];
        r = fmaf(wc, c0, r);
        g = fmaf(wc, c1, g);
        b = fmaf(wc, c2, b);
    }
    cr = fminf(fmaxf(r + 0.5f, 0.0f), 100000.0f);
    cg = fminf(fmaxf(g + 0.5f, 0.0f), 100000.0f);
    cb = fminf(fmaxf(b + 0.5f, 0.0f), 100000.0f);
}

// ---- f32 fallback color (round-2 path, used if ws too small) ----
__device__ __forceinline__ void eval_color_f(float px, float py, float pz,
                                             const float* __restrict__ grid,
                                             const SH9& sh,
                                             float& cr, float& cg, float& cb) {
    int ibase; float wxs[2], wys[2], wzs[2];
    pos_to_cell(px, py, pz, ibase, wxs, wys, wzs);
    float r = 0.0f, g = 0.0f, b = 0.0f;
    #pragma unroll
    for (int cx = 0; cx < 2; ++cx)
    #pragma unroll
    for (int cy = 0; cy < 2; ++cy)
    #pragma unroll
    for (int cz = 0; cz < 2; ++cz) {
        int idx = ibase + (cx << 14) + (cy << 7) + cz;
        float wc = wxs[cx] * wys[cy] * wzs[cz];
        const float* cp = grid + (size_t)idx * 27;
        f32x4 v0 = load4(cp);
        f32x4 v1 = load4(cp + 4);
        f32x4 v2 = load4(cp + 8);
        f32x4 v3 = load4(cp + 12);
        f32x4 v4 = load4(cp + 16);
        f32x4 v5 = load4(cp + 20);
        f32x4 v6 = load4(cp + 23);
        float c0 = sh.a*v0.x + sh.b*v0.y + sh.c*v0.z + sh.d*v0.w
                 + sh.e*v1.x + sh.f*v1.y + sh.g*v1.z + sh.h*v1.w + sh.i*v2.x;
        float c1 = sh.a*v2.y + sh.b*v2.z + sh.c*v2.w + sh.d*v3.x
                 + sh.e*v3.y + sh.f*v3.z + sh.g*v3.w + sh.h*v4.x + sh.i*v4.y;
        float c2 = sh.a*v4.z + sh.b*v4.w + sh.c*v5.x + sh.d*v5.y
                 + sh.e*v5.z + sh.f*v5.w + sh.g*v6.y + sh.h*v6.z + sh.i*v6.w;
        r = fmaf(wc, c0, r);
        g = fmaf(wc, c1, g);
        b = fmaf(wc, c2, b);
    }
    cr = fminf(fmaxf(r + 0.5f, 0.0f), 100000.0f);
    cg = fminf(fmaxf(g + 0.5f, 0.0f), 100000.0f);
    cb = fminf(fmaxf(b + 0.5f, 0.0f), 100000.0f);
}

__device__ __forceinline__ float wave_incl_scan(float v, int lane) {
    #pragma unroll
    for (int off = 1; off < 64; off <<= 1) {
        float n = __shfl_up(v, (unsigned)off, 64);
        if (lane >= off) v += n;
    }
    return v;
}

// ---- prepass: grid f32[2M][27] -> packed fp16 [2M][32] (64 B/cell, aligned) ----
__global__ __launch_bounds__(256) void pack_kernel(const float* __restrict__ grid,
                                                   _Float16* __restrict__ pack) {
    int cell = blockIdx.x * blockDim.x + threadIdx.x;
    if (cell >= NCELLS) return;
    const float* src = grid + (size_t)cell * 27;
    float t[28];
    f32x4 a0 = load4(src);      f32x4 a1 = load4(src + 4);
    f32x4 a2 = load4(src + 8);  f32x4 a3 = load4(src + 12);
    f32x4 a4 = load4(src + 16); f32x4 a5 = load4(src + 20);
    t[0]=a0.x;t[1]=a0.y;t[2]=a0.z;t[3]=a0.w;
    t[4]=a1.x;t[5]=a1.y;t[6]=a1.z;t[7]=a1.w;
    t[8]=a2.x;t[9]=a2.y;t[10]=a2.z;t[11]=a2.w;
    t[12]=a3.x;t[13]=a3.y;t[14]=a3.z;t[15]=a3.w;
    t[16]=a4.x;t[17]=a4.y;t[18]=a4.z;t[19]=a4.w;
    t[20]=a5.x;t[21]=a5.y;t[22]=a5.z;t[23]=a5.w;
    t[24]=src[24];t[25]=src[25];t[26]=src[26];t[27]=0.0f;
    h16x8 o0, o1, o2;
    h16x4 o3;
    #pragma unroll
    for (int i = 0; i < 8; ++i) { o0[i]=(_Float16)t[i]; o1[i]=(_Float16)t[8+i]; o2[i]=(_Float16)t[16+i]; }
    #pragma unroll
    for (int i = 0; i < 4; ++i) o3[i]=(_Float16)t[24+i];
    _Float16* dst = pack + ((size_t)cell << 5);
    __builtin_memcpy(dst,      &o0, 16);
    __builtin_memcpy(dst + 8,  &o1, 16);
    __builtin_memcpy(dst + 16, &o2, 16);
    __builtin_memcpy(dst + 24, &o3, 8);
}

template <bool PACKED>
__global__ __launch_bounds__(256) void rf_kernel(
    const float* __restrict__ x, const float* __restrict__ d,
    const float* __restrict__ tmin, const float* __restrict__ tmax,
    const float* __restrict__ grid, const _Float16* __restrict__ pack,
    const float* __restrict__ opa,
    float* __restrict__ out, int nrays)
{
    int gtid = blockIdx.x * blockDim.x + threadIdx.x;
    int ray = __builtin_amdgcn_readfirstlane(gtid >> 6);
    int lane = threadIdx.x & 63;
    if (ray >= nrays) return;

    float ox = x[3*ray+0], oy = x[3*ray+1], oz = x[3*ray+2];
    float ddx = d[3*ray+0], ddy = d[3*ray+1], ddz = d[3*ray+2];
    float t0 = tmin[ray], t1 = tmax[ray];
    float range = t1 - t0;
    float delta = range * 0.0078125f;

    SH9 sh;
    sh.a = 0.28209479177387814f;
    sh.b = -0.4886025119029199f * ddy;
    sh.c =  0.4886025119029199f * ddz;
    sh.d = -0.4886025119029199f * ddx;
    sh.e =  1.0925484305920792f * ddx * ddy;
    sh.f = -1.0925484305920792f * ddy * ddz;
    sh.g =  0.31539156525252005f * (2.0f*ddz*ddz - ddx*ddx - ddy*ddy);
    sh.h = -1.0925484305920792f * ddx * ddz;
    sh.i =  0.5462742152960396f * (ddx*ddx - ddy*ddy);

    float accR = 0.0f, accG = 0.0f, accB = 0.0f;

    {
        int s = lane;
        float t = range * (0.05f + (float)s * 0.0078125f) + t0;
        float px = ox + t*ddx, py = oy + t*ddy, pz = oz + t*ddz;
        float opv = eval_op(px, py, pz, opa);
        float dts = -delta * opv;
        float incl = wave_incl_scan(dts, lane);
        float cum = incl - dts;
        float total0 = __shfl(incl, 63, 64);
        float w = __expf(cum) * (1.0f - __expf(dts));
        if (w > WEPS) {
            float cr, cg, cb;
            if (PACKED) eval_color_h(px, py, pz, pack, sh, cr, cg, cb);
            else        eval_color_f(px, py, pz, grid, sh, cr, cg, cb);
            accR = w * cr; accG = w * cg; accB = w * cb;
        }
        if (total0 > LOG_TSKIP) {
            int s1 = 64 + lane;
            float dts1 = 0.0f;
            float px1 = 0.f, py1 = 0.f, pz1 = 0.f;
            if (s1 < NS) {
                float t1s = range * (0.05f + (float)s1 * 0.0078125f) + t0;
                px1 = ox + t1s*ddx; py1 = oy + t1s*ddy; pz1 = oz + t1s*ddz;
                float opv1 = eval_op(px1, py1, pz1, opa);
                dts1 = -delta * opv1;
            }
            float incl1 = wave_incl_scan(dts1, lane);
            float cum1 = total0 + incl1 - dts1;
            float w1 = __expf(cum1) * (1.0f - __expf(dts1));
            if (w1 > WEPS) {
                float cr, cg, cb;
                if (PACKED) eval_color_h(px1, py1, pz1, pack, sh, cr, cg, cb);
                else        eval_color_f(px1, py1, pz1, grid, sh, cr, cg, cb);
                accR = fmaf(w1, cr, accR);
                accG = fmaf(w1, cg, accG);
                accB = fmaf(w1, cb, accB);
            }
        }
    }

    #pragma unroll
    for (int off = 32; off > 0; off >>= 1) {
        accR += __shfl_xor(accR, off, 64);
        accG += __shfl_xor(accG, off, 64);
        accB += __shfl_xor(accB, off, 64);
    }
    if (lane == 0) {
        out[3*ray+0] = accR;
        out[3*ray+1] = accG;
        out[3*ray+2] = accB;
    }
}

extern "C" void kernel_launch(void* const* d_in, const int* in_sizes, int n_in,
                              void* d_out, int out_size, void* d_ws, size_t ws_size,
                              hipStream_t stream) {
    const float* x    = (const float*)d_in[0];
    const float* d    = (const float*)d_in[1];
    const float* tmin = (const float*)d_in[2];
    const float* tmax = (const float*)d_in[3];
    const float* grid = (const float*)d_in[4];
    const float* opa  = (const float*)d_in[5];
    float* out = (float*)d_out;

    int nrays = in_sizes[0] / 3;                 // 32768
    int threads = 256;
    int blocks = (nrays * 64 + threads - 1) / threads;   // 8192

    if (ws_size >= PACK_BYTES) {
        _Float16* pack = (_Float16*)d_ws;
        pack_kernel<<<(NCELLS + 255) / 256, 256, 0, stream>>>(grid, pack);
        rf_kernel<true><<<blocks, threads, 0, stream>>>(x, d, tmin, tmax, grid, pack, opa, out, nrays);
    } else {
        rf_kernel<false><<<blocks, threads, 0, stream>>>(x, d, tmin, tmax, grid, nullptr, opa, out, nrays);
    }
}

// Round 4
// 430.301 us; speedup vs baseline: 1.0402x; 1.0402x over previous
//
#include <hip/hip_runtime.h>

#define NS 115              // contributing samples (S=116, last one unused)
#define WEPS 5e-5f          // per-sample color skip
#define LOG_TSKIP -6.9078f  // chunk1 skip when T < 1e-3
#define NCELLS (128*128*128)
#define PACK_BYTES ((size_t)NCELLS * 64)
#define CPB 128             // cells per pack block

typedef float f32x4 __attribute__((ext_vector_type(4)));
typedef float f32x2 __attribute__((ext_vector_type(2)));
typedef _Float16 h16x8 __attribute__((ext_vector_type(8)));
typedef _Float16 h16x4 __attribute__((ext_vector_type(4)));
typedef unsigned short u16x8 __attribute__((ext_vector_type(8)));

struct SH9 { float a,b,c,d,e,f,g,h,i; };

__device__ __forceinline__ f32x4 load4(const float* p) { f32x4 v; __builtin_memcpy(&v, p, 16); return v; }
__device__ __forceinline__ f32x2 load2(const float* p) { f32x2 v; __builtin_memcpy(&v, p, 8);  return v; }
__device__ __forceinline__ h16x8 load8h(const _Float16* p) { h16x8 v; __builtin_memcpy(&v, p, 16); return v; }
__device__ __forceinline__ h16x4 load4h(const _Float16* p) { h16x4 v; __builtin_memcpy(&v, p, 8);  return v; }

__device__ __forceinline__ void pos_to_cell(float px, float py, float pz,
                                            int& ibase, float* wxs, float* wys, float* wzs) {
    px = fminf(fmaxf(px, 0.0f), 126.9999f);
    py = fminf(fmaxf(py, 0.0f), 126.9999f);
    pz = fminf(fmaxf(pz, 0.0f), 126.9999f);
    int ix = (int)px, iy = (int)py, iz = (int)pz;
    float wx = px - (float)ix, wy = py - (float)iy, wz = pz - (float)iz;
    ibase = (ix << 14) + (iy << 7) + iz;
    wxs[0] = 1.0f - wx; wxs[1] = wx;
    wys[0] = 1.0f - wy; wys[1] = wy;
    wzs[0] = 1.0f - wz; wzs[1] = wz;
}

// opacity trilerp on the ORIGINAL f32 array (8.4 MB, L3-resident; keeps
// exponent-path precision); z-adjacent corners via dwordx2.
__device__ __forceinline__ float eval_op(float px, float py, float pz,
                                         const float* __restrict__ opa) {
    int ibase; float wxs[2], wys[2], wzs[2];
    pos_to_cell(px, py, pz, ibase, wxs, wys, wzs);
    float op = 0.0f;
    #pragma unroll
    for (int cx = 0; cx < 2; ++cx)
    #pragma unroll
    for (int cy = 0; cy < 2; ++cy) {
        int idx = ibase + (cx << 14) + (cy << 7);
        f32x2 pr = load2(opa + idx);
        float wxy = wxs[cx] * wys[cy];
        op = fmaf(wxy * wzs[0], pr.x, op);
        op = fmaf(wxy * wzs[1], pr.y, op);
    }
    return fminf(fmaxf(op, 0.0f), 100000.0f);
}

// ---- packed fp16 color: one 64-B aligned cache line per corner ----
__device__ __forceinline__ void eval_color_h(float px, float py, float pz,
                                             const _Float16* __restrict__ pack,
                                             const SH9& sh,
                                             float& cr, float& cg, float& cb) {
    int ibase; float wxs[2], wys[2], wzs[2];
    pos_to_cell(px, py, pz, ibase, wxs, wys, wzs);
    float r = 0.0f, g = 0.0f, b = 0.0f;
    #pragma unroll
    for (int cx = 0; cx < 2; ++cx)
    #pragma unroll
    for (int cy = 0; cy < 2; ++cy)
    #pragma unroll
    for (int cz = 0; cz < 2; ++cz) {
        int idx = ibase + (cx << 14) + (cy << 7) + cz;
        float wc = wxs[cx] * wys[cy] * wzs[cz];
        const _Float16* cp = pack + ((size_t)idx << 5);
        h16x8 v0 = load8h(cp);        // ch 0..7
        h16x8 v1 = load8h(cp + 8);    // ch 8..15
        h16x8 v2 = load8h(cp + 16);   // ch 16..23
        h16x4 v3 = load4h(cp + 24);   // ch 24..26 (+pad)
        float c0 = sh.a*(float)v0[0] + sh.b*(float)v0[1] + sh.c*(float)v0[2] + sh.d*(float)v0[3]
                 + sh.e*(float)v0[4] + sh.f*(float)v0[5] + sh.g*(float)v0[6] + sh.h*(float)v0[7]
                 + sh.i*(float)v1[0];
        float c1 = sh.a*(float)v1[1] + sh.b*(float)v1[2] + sh.c*(float)v1[3] + sh.d*(float)v1[4]
                 + sh.e*(float)v1[5] + sh.f*(float)v1[6] + sh.g*(float)v1[7] + sh.h*(float)v2[0]
                 + sh.i*(float)v2[1];
        float c2 = sh.a*(float)v2[2] + sh.b*(float)v2[3] + sh.c*(float)v2[4] + sh.d*(float)v2[5]
                 + sh.e*(float)v2[6] + sh.f*(float)v2[7] + sh.g*(float)v3[0] + sh.h*(float)v3[1]
                 + sh.i*(float)v3[2];
        r = fmaf(wc, c0, r);
        g = fmaf(wc, c1, g);
        b = fmaf(wc, c2, b);
    }
    cr = fminf(fmaxf(r + 0.5f, 0.0f), 100000.0f);
    cg = fminf(fmaxf(g + 0.5f, 0.0f), 100000.0f);
    cb = fminf(fmaxf(b + 0.5f, 0.0f), 100000.0f);
}

// ---- f32 fallback color (used if ws too small) ----
__device__ __forceinline__ void eval_color_f(float px, float py, float pz,
                                             const float* __restrict__ grid,
                                             const SH9& sh,
                                             float& cr, float& cg, float& cb) {
    int ibase; float wxs[2], wys[2], wzs[2];
    pos_to_cell(px, py, pz, ibase, wxs, wys, wzs);
    float r = 0.0f, g = 0.0f, b = 0.0f;
    #pragma unroll
    for (int cx = 0; cx < 2; ++cx)
    #pragma unroll
    for (int cy = 0; cy < 2; ++cy)
    #pragma unroll
    for (int cz = 0; cz < 2; ++cz) {
        int idx = ibase + (cx << 14) + (cy << 7) + cz;
        float wc = wxs[cx] * wys[cy] * wzs[cz];
        const float* cp = grid + (size_t)idx * 27;
        f32x4 v0 = load4(cp);
        f32x4 v1 = load4(cp + 4);
        f32x4 v2 = load4(cp + 8);
        f32x4 v3 = load4(cp + 12);
        f32x4 v4 = load4(cp + 16);
        f32x4 v5 = load4(cp + 20);
        f32x4 v6 = load4(cp + 23);
        float c0 = sh.a*v0.x + sh.b*v0.y + sh.c*v0.z + sh.d*v0.w
                 + sh.e*v1.x + sh.f*v1.y + sh.g*v1.z + sh.h*v1.w + sh.i*v2.x;
        float c1 = sh.a*v2.y + sh.b*v2.z + sh.c*v2.w + sh.d*v3.x
                 + sh.e*v3.y + sh.f*v3.z + sh.g*v3.w + sh.h*v4.x + sh.i*v4.y;
        float c2 = sh.a*v4.z + sh.b*v4.w + sh.c*v5.x + sh.d*v5.y
                 + sh.e*v5.z + sh.f*v5.w + sh.g*v6.y + sh.h*v6.z + sh.i*v6.w;
        r = fmaf(wc, c0, r);
        g = fmaf(wc, c1, g);
        b = fmaf(wc, c2, b);
    }
    cr = fminf(fmaxf(r + 0.5f, 0.0f), 100000.0f);
    cg = fminf(fmaxf(g + 0.5f, 0.0f), 100000.0f);
    cb = fminf(fmaxf(b + 0.5f, 0.0f), 100000.0f);
}

__device__ __forceinline__ float wave_incl_scan(float v, int lane) {
    #pragma unroll
    for (int off = 1; off < 64; off <<= 1) {
        float n = __shfl_up(v, (unsigned)off, 64);
        if (lane >= off) v += n;
    }
    return v;
}

// ---- prepass v2: LDS-staged, fully-coalesced f32[*][27] -> fp16[*][32] ----
// Each 256-thread block packs 128 cells: coalesced dwordx4 read of the
// contiguous 13824-B f32 span -> LDS; 2 threads/cell convert via LDS
// (stride-27 reads = <=2-way bank alias = free); coalesced dwordx4 writeout.
__global__ __launch_bounds__(256) void pack_kernel(const float* __restrict__ grid,
                                                   _Float16* __restrict__ pack) {
    __shared__ float   s_in[CPB * 27];        // 13824 B
    __shared__ unsigned short s_out[CPB * 32]; // 8192 B
    const int t = threadIdx.x;
    const long long c0 = (long long)blockIdx.x * CPB;
    const float* src = grid + c0 * 27;

    // load: 3456 floats = 864 f32x4, threads grab strided vec4 (coalesced)
    #pragma unroll
    for (int k = 0; k < 4; ++k) {
        int idx = k * 256 + t;
        if (idx < (CPB * 27) / 4) {
            f32x4 v = load4(src + idx * 4);
            __builtin_memcpy(&s_in[idx * 4], &v, 16);
        }
    }
    __syncthreads();

    // convert: 2 threads per cell, 16 channels each
    {
        int lc = t >> 1;            // local cell 0..127
        int h  = t & 1;             // half 0: ch0..15, half 1: ch16..31(pad)
        const float* in = &s_in[lc * 27 + h * 16];
        unsigned short* outp = &s_out[lc * 32 + h * 16];
        int nvalid = h ? 11 : 16;   // ch 27..31 are pad
        #pragma unroll
        for (int j = 0; j < 16; ++j) {
            _Float16 hv = (j < nvalid) ? (_Float16)in[j] : (_Float16)0.0f;
            unsigned short u; __builtin_memcpy(&u, &hv, 2);
            outp[j] = u;
        }
    }
    __syncthreads();

    // writeout: 8192 B = 512 x 16B, coalesced dwordx4
    unsigned short* dst = (unsigned short*)(pack + (c0 << 5));
    #pragma unroll
    for (int k = 0; k < 2; ++k) {
        int idx = k * 256 + t;
        u16x8 v; __builtin_memcpy(&v, &s_out[idx * 8], 16);
        __builtin_memcpy(dst + idx * 8, &v, 16);
    }
}

template <bool PACKED>
__global__ __launch_bounds__(256) void rf_kernel(
    const float* __restrict__ x, const float* __restrict__ d,
    const float* __restrict__ tmin, const float* __restrict__ tmax,
    const float* __restrict__ grid, const _Float16* __restrict__ pack,
    const float* __restrict__ opa,
    float* __restrict__ out, int nrays)
{
    int gtid = blockIdx.x * blockDim.x + threadIdx.x;
    int ray = __builtin_amdgcn_readfirstlane(gtid >> 6);
    int lane = threadIdx.x & 63;
    if (ray >= nrays) return;

    float ox = x[3*ray+0], oy = x[3*ray+1], oz = x[3*ray+2];
    float ddx = d[3*ray+0], ddy = d[3*ray+1], ddz = d[3*ray+2];
    float t0 = tmin[ray], t1 = tmax[ray];
    float range = t1 - t0;
    float delta = range * 0.0078125f;

    SH9 sh;
    sh.a = 0.28209479177387814f;
    sh.b = -0.4886025119029199f * ddy;
    sh.c =  0.4886025119029199f * ddz;
    sh.d = -0.4886025119029199f * ddx;
    sh.e =  1.0925484305920792f * ddx * ddy;
    sh.f = -1.0925484305920792f * ddy * ddz;
    sh.g =  0.31539156525252005f * (2.0f*ddz*ddz - ddx*ddx - ddy*ddy);
    sh.h = -1.0925484305920792f * ddx * ddz;
    sh.i =  0.5462742152960396f * (ddx*ddx - ddy*ddy);

    float accR = 0.0f, accG = 0.0f, accB = 0.0f;

    {
        int s = lane;
        float t = range * (0.05f + (float)s * 0.0078125f) + t0;
        float px = ox + t*ddx, py = oy + t*ddy, pz = oz + t*ddz;
        float opv = eval_op(px, py, pz, opa);
        float dts = -delta * opv;
        float incl = wave_incl_scan(dts, lane);
        float cum = incl - dts;
        float total0 = __shfl(incl, 63, 64);
        float w = __expf(cum) * (1.0f - __expf(dts));
        if (w > WEPS) {
            float cr, cg, cb;
            if (PACKED) eval_color_h(px, py, pz, pack, sh, cr, cg, cb);
            else        eval_color_f(px, py, pz, grid, sh, cr, cg, cb);
            accR = w * cr; accG = w * cg; accB = w * cb;
        }
        if (total0 > LOG_TSKIP) {
            int s1 = 64 + lane;
            float dts1 = 0.0f;
            float px1 = 0.f, py1 = 0.f, pz1 = 0.f;
            if (s1 < NS) {
                float t1s = range * (0.05f + (float)s1 * 0.0078125f) + t0;
                px1 = ox + t1s*ddx; py1 = oy + t1s*ddy; pz1 = oz + t1s*ddz;
                float opv1 = eval_op(px1, py1, pz1, opa);
                dts1 = -delta * opv1;
            }
            float incl1 = wave_incl_scan(dts1, lane);
            float cum1 = total0 + incl1 - dts1;
            float w1 = __expf(cum1) * (1.0f - __expf(dts1));
            if (w1 > WEPS) {
                float cr, cg, cb;
                if (PACKED) eval_color_h(px1, py1, pz1, pack, sh, cr, cg, cb);
                else        eval_color_f(px1, py1, pz1, grid, sh, cr, cg, cb);
                accR = fmaf(w1, cr, accR);
                accG = fmaf(w1, cg, accG);
                accB = fmaf(w1, cb, accB);
            }
        }
    }

    #pragma unroll
    for (int off = 32; off > 0; off >>= 1) {
        accR += __shfl_xor(accR, off, 64);
        accG += __shfl_xor(accG, off, 64);
        accB += __shfl_xor(accB, off, 64);
    }
    if (lane == 0) {
        out[3*ray+0] = accR;
        out[3*ray+1] = accG;
        out[3*ray+2] = accB;
    }
}

extern "C" void kernel_launch(void* const* d_in, const int* in_sizes, int n_in,
                              void* d_out, int out_size, void* d_ws, size_t ws_size,
                              hipStream_t stream) {
    const float* x    = (const float*)d_in[0];
    const float* d    = (const float*)d_in[1];
    const float* tmin = (const float*)d_in[2];
    const float* tmax = (const float*)d_in[3];
    const float* grid = (const float*)d_in[4];
    const float* opa  = (const float*)d_in[5];
    float* out = (float*)d_out;

    int nrays = in_sizes[0] / 3;                 // 32768
    int threads = 256;
    int blocks = (nrays * 64 + threads - 1) / threads;   // 8192

    if (ws_size >= PACK_BYTES) {
        _Float16* pack = (_Float16*)d_ws;
        pack_kernel<<<NCELLS / CPB, 256, 0, stream>>>(grid, pack);
        rf_kernel<true><<<blocks, threads, 0, stream>>>(x, d, tmin, tmax, grid, pack, opa, out, nrays);
    } else {
        rf_kernel<false><<<blocks, threads, 0, stream>>>(x, d, tmin, tmax, grid, nullptr, opa, out, nrays);
    }
}